// Round 5
// baseline (121.489 us; speedup 1.0000x reference)
//
#include <hip/hip_runtime.h>
#include <hip/hip_bf16.h>

typedef __bf16 bf16x8 __attribute__((ext_vector_type(8)));
typedef float f32x4 __attribute__((ext_vector_type(4)));

// Pre-kernel: clusters (128x512 f32) -> bf16 in ws, plus fp32 c2[128].
__global__ __launch_bounds__(64)
void prep_clusters(const float* __restrict__ c, __bf16* __restrict__ cb,
                   float* __restrict__ c2)
{
    const int row = blockIdx.x;     // 0..127
    const int l = threadIdx.x;      // 0..63
    const float* p = c + row * 512 + l * 8;
    f32x4 u0 = *(const f32x4*)p;
    f32x4 u1 = *(const f32x4*)(p + 4);
    bf16x8 v;
    float s = 0.f;
#pragma unroll
    for (int j = 0; j < 4; ++j) {
        v[j]     = (__bf16)u0[j];
        v[4 + j] = (__bf16)u1[j];
        s += u0[j] * u0[j] + u1[j] * u1[j];
    }
    *(bf16x8*)(cb + row * 512 + l * 8) = v;
#pragma unroll
    for (int off = 32; off >= 1; off >>= 1) s += __shfl_xor(s, off);
    if (l == 0) c2[row] = s;
}

__device__ __forceinline__ void gl_lds16(const float* g, float* l)
{
    __builtin_amdgcn_global_load_lds(
        (const __attribute__((address_space(1))) void*)g,
        (__attribute__((address_space(3))) void*)l, 16, 0, 0);
}

// Wave-private pipeline, 2x8KB LDS dbuf per wave, both-sides XOR swizzle.
// NEW vs R4: B (cluster) fragments are prefetched ONE ITERATION AHEAD into a
// ping-pong register pair, so the per-iteration vmcnt never waits on an
// L2 load issued moments before — it only drains loads issued a full
// iteration earlier. s_setprio(1) wraps the MFMA cluster (T5).
__global__ __launch_bounds__(256, 2)
void cluster_q_mfma(const float* __restrict__ x,
                    const __bf16* __restrict__ cb,
                    const float* __restrict__ c2,
                    float* __restrict__ out)
{
    __shared__ float lds[4][2][2048];   // [wave][buf][64 rows x 32 k]

    const int tid = threadIdx.x;
    const int l = tid & 63;
    const int w = tid >> 6;
    const int m = l & 15;          // fragment row (A) / col (B)
    const int g = l >> 4;          // k-group (0..3), 8 contiguous k
    const long wrow = (long)blockIdx.x * 256 + w * 64;

    f32x4 acc[4][8];
#pragma unroll
    for (int i = 0; i < 4; ++i)
#pragma unroll
        for (int j = 0; j < 8; ++j) acc[i][j] = f32x4{0.f, 0.f, 0.f, 0.f};

    float x2p[4] = {0.f, 0.f, 0.f, 0.f};

    // Staging: instr i covers rows [i*8, i*8+8); lane handles row i*8+(l>>3),
    // source 16B-chunk (l&7)^(l>>3)  (pre-swizzle for the linear LDS write).
    const float* sbase = x + (wrow + (l >> 3)) * 512 + ((l & 7) ^ (l >> 3)) * 4;

    const __bf16* cbp = cb + m * 512 + g * 8;

#define STAGE(BUF, K0)                                                    \
    { _Pragma("unroll")                                                   \
      for (int i_ = 0; i_ < 8; ++i_)                                      \
          gl_lds16(sbase + (long)i_ * (8 * 512) + (K0),                   \
                   &lds[w][BUF][i_ * 256]); }

#define LOADB(BF, KB)                                                     \
    { _Pragma("unroll")                                                   \
      for (int nb_ = 0; nb_ < 8; ++nb_)                                   \
          BF[nb_] = *(const bf16x8*)(cbp + nb_ * (16 * 512) + (KB)); }

#define COMPUTE(BUF, BF)                                                  \
    {                                                                     \
        bf16x8 aF[4];                                                     \
        _Pragma("unroll")                                                 \
        for (int rb = 0; rb < 4; ++rb) {                                  \
            const int row_ = m + rb * 16;                                 \
            const float* bw_ = &lds[w][BUF][0] + row_ * 32;               \
            f32x4 u0 = *(const f32x4*)(bw_ + (((2 * g)     ^ (m & 7)) * 4)); \
            f32x4 u1 = *(const f32x4*)(bw_ + (((2 * g + 1) ^ (m & 7)) * 4)); \
            _Pragma("unroll")                                             \
            for (int j = 0; j < 4; ++j) {                                 \
                aF[rb][j]     = (__bf16)u0[j];                            \
                aF[rb][4 + j] = (__bf16)u1[j];                            \
                x2p[rb] += u0[j] * u0[j];                                 \
                x2p[rb] += u1[j] * u1[j];                                 \
            }                                                             \
        }                                                                 \
        __builtin_amdgcn_s_setprio(1);                                    \
        _Pragma("unroll")                                                 \
        for (int rb = 0; rb < 4; ++rb) {                                  \
            _Pragma("unroll")                                             \
            for (int nb = 0; nb < 8; ++nb)                                \
                acc[rb][nb] = __builtin_amdgcn_mfma_f32_16x16x32_bf16(    \
                    aF[rb], BF[nb], acc[rb][nb], 0, 0, 0);                \
        }                                                                 \
        __builtin_amdgcn_s_setprio(0);                                    \
    }

#define SB __builtin_amdgcn_sched_barrier(0)

    bf16x8 bFe[8], bFo[8];

    STAGE(0, 0);                // tile 0 in flight
    LOADB(bFe, 0);              // B(0) in flight

#pragma unroll 1
    for (int tt = 0; tt < 8; ++tt) {
        const int kb = tt * 64;

        // ---- even iteration t=2tt: compute buf0 with bFe ----
        asm volatile("s_waitcnt lgkmcnt(0)" ::: "memory");  // WAR on buf1
        SB;
        STAGE(1, kb + 32);                   // stage t+1
        LOADB(bFo, kb + 32);                 // prefetch B(t+1)
        SB;
        asm volatile("s_waitcnt vmcnt(16)" ::: "memory");   // drain S(t)+B(t)
        SB;
        COMPUTE(0, bFe);

        // ---- odd iteration t=2tt+1: compute buf1 with bFo ----
        if (tt < 7) {
            asm volatile("s_waitcnt lgkmcnt(0)" ::: "memory");  // WAR on buf0
            SB;
            STAGE(0, kb + 64);               // stage t+2
            LOADB(bFe, kb + 64);             // prefetch B(t+2)
            SB;
            asm volatile("s_waitcnt vmcnt(16)" ::: "memory");   // drain S(t+1)+B(t+1)
            SB;
        } else {
            asm volatile("s_waitcnt vmcnt(0)" ::: "memory");    // final drain
            SB;
        }
        COMPUTE(1, bFo);
    }
#undef STAGE
#undef LOADB
#undef COMPUTE
#undef SB

    // Complete x2 across the 4 k-groups (lanes m, m+16, m+32, m+48).
#pragma unroll
    for (int rb = 0; rb < 4; ++rb) {
        x2p[rb] += __shfl_xor(x2p[rb], 16);
        x2p[rb] += __shfl_xor(x2p[rb], 32);
    }

    float c2v[8];
#pragma unroll
    for (int nb = 0; nb < 8; ++nb) c2v[nb] = c2[nb * 16 + m];

    // Epilogue. C/D layout: col = m, row(within 16-block) = g*4 + r.
#pragma unroll
    for (int rb = 0; rb < 4; ++rb) {
        float x2r[4], rs[4];
#pragma unroll
        for (int r = 0; r < 4; ++r) {
            x2r[r] = __shfl(x2p[rb], g * 4 + r);
            rs[r] = 0.f;
        }
#pragma unroll
        for (int nb = 0; nb < 8; ++nb) {
#pragma unroll
            for (int r = 0; r < 4; ++r) {
                float d2 = x2r[r] + c2v[nb] - 2.f * acc[rb][nb][r];
                d2 = fmaxf(d2, 0.f);
                float q = 1.f / (1.f + d2);   // ALPHA=1 -> exponent is 1
                acc[rb][nb][r] = q;
                rs[r] += q;
            }
        }
#pragma unroll
        for (int r = 0; r < 4; ++r) {
            rs[r] += __shfl_xor(rs[r], 1);
            rs[r] += __shfl_xor(rs[r], 2);
            rs[r] += __shfl_xor(rs[r], 4);
            rs[r] += __shfl_xor(rs[r], 8);
            rs[r] = 1.f / rs[r];
        }
        const long orow = wrow + rb * 16 + g * 4;
#pragma unroll
        for (int nb = 0; nb < 8; ++nb) {
#pragma unroll
            for (int r = 0; r < 4; ++r) {
                out[(orow + r) * 128 + nb * 16 + m] = acc[rb][nb][r] * rs[r];
            }
        }
    }
}

extern "C" void kernel_launch(void* const* d_in, const int* in_sizes, int n_in,
                              void* d_out, int out_size, void* d_ws, size_t ws_size,
                              hipStream_t stream)
{
    const float* x = (const float*)d_in[0];
    const float* c = (const float*)d_in[1];
    float* out = (float*)d_out;

    float*  c2ws = (float*)d_ws;                        // 128 floats
    __bf16* cbws = (__bf16*)((char*)d_ws + 1024);       // 128x512 bf16 = 128 KB

    hipLaunchKernelGGL(prep_clusters, dim3(128), dim3(64), 0, stream, c, cbws, c2ws);

    const int N = in_sizes[0] / 512;                    // 131072 rows
    dim3 grid(N / 256), block(256);                     // 512 blocks = 2/CU
    hipLaunchKernelGGL(cluster_q_mfma, grid, block, 0, stream, x, cbws, c2ws, out);
}

// Round 6
// 89.494 us; speedup vs baseline: 1.3575x; 1.3575x over previous
//
#include <hip/hip_runtime.h>
#include <hip/hip_bf16.h>

typedef __bf16 bf16x8 __attribute__((ext_vector_type(8)));
typedef float f32x4 __attribute__((ext_vector_type(4)));

// Pre-kernel: clusters (128x512 f32) -> bf16 in ws, plus fp32 c2[128].
__global__ __launch_bounds__(64)
void prep_clusters(const float* __restrict__ c, __bf16* __restrict__ cb,
                   float* __restrict__ c2)
{
    const int row = blockIdx.x;     // 0..127
    const int l = threadIdx.x;      // 0..63
    const float* p = c + row * 512 + l * 8;
    f32x4 u0 = *(const f32x4*)p;
    f32x4 u1 = *(const f32x4*)(p + 4);
    bf16x8 v;
    float s = 0.f;
#pragma unroll
    for (int j = 0; j < 4; ++j) {
        v[j]     = (__bf16)u0[j];
        v[4 + j] = (__bf16)u1[j];
        s += u0[j] * u0[j] + u1[j] * u1[j];
    }
    *(bf16x8*)(cb + row * 512 + l * 8) = v;
#pragma unroll
    for (int off = 32; off >= 1; off >>= 1) s += __shfl_xor(s, off);
    if (l == 0) c2[row] = s;
}

__device__ __forceinline__ void gl_lds16(const float* g, float* l)
{
    __builtin_amdgcn_global_load_lds(
        (const __attribute__((address_space(1))) void*)g,
        (__attribute__((address_space(3))) void*)l, 16, 0, 0);
}

// OCCUPANCY RESTRUCTURE: block = 128 threads (2 waves) owning 64 rows.
// Wave w computes 64 rows x 64 cols (cols w*64..w*64+63) -> acc = 64 VGPRs
// -> 4 waves/SIMD (16 waves/CU, 8 independent blocks/CU). Simple 2-barrier
// double-buffered LDS pipeline with counted vmcnt(4). Row sums are exchanged
// between the two waves through a small LDS array.
__global__ __launch_bounds__(128, 4)
void cluster_q_mfma(const float* __restrict__ x,
                    const __bf16* __restrict__ cb,
                    const float* __restrict__ c2,
                    float* __restrict__ out)
{
    __shared__ float lds[2][2048];   // [buf][64 rows x 32 k] = 16 KB
    __shared__ float rsx[2][64];     // per-wave partial row sums

    const int tid = threadIdx.x;    // 0..127
    const int l = tid & 63;
    const int w = tid >> 6;         // wave: 0 or 1 (column half)
    const int m = l & 15;           // fragment row (A) / col (B)
    const int g = l >> 4;           // k-group (0..3)
    const long brow = (long)blockIdx.x * 64;

    f32x4 acc[4][4];
#pragma unroll
    for (int i = 0; i < 4; ++i)
#pragma unroll
        for (int j = 0; j < 4; ++j) acc[i][j] = f32x4{0.f, 0.f, 0.f, 0.f};

    float x2p[4] = {0.f, 0.f, 0.f, 0.f};

    // Staging: wave w stages rows [w*32, w*32+32). Instr i_: rows w*32+i_*8+(l>>3),
    // source chunk (l&7)^(l>>3) (pre-swizzle; LDS write is linear lane*16B).
    const float* sbase = x + (brow + w * 32 + (l >> 3)) * 512
                           + ((l & 7) ^ (l >> 3)) * 4;
    const int doff = w * 1024;      // w*32 rows * 32 floats

    const __bf16* cbp = cb + (w * 64 + m) * 512 + g * 8;

#define SB __builtin_amdgcn_sched_barrier(0)
#define STAGE(BUF, K0)                                                    \
    { _Pragma("unroll")                                                   \
      for (int i_ = 0; i_ < 4; ++i_)                                      \
          gl_lds16(sbase + (long)i_ * (8 * 512) + (K0),                   \
                   &lds[BUF][doff + i_ * 256]); }

    STAGE(0, 0);                    // tile 0 in flight

#pragma unroll 1
    for (int it = 0; it < 16; ++it) {
        const int cur = it & 1;
        const int kb = it * 32;

        // B fragments for this k-step (4 x 16B from L2-resident bf16 ws).
        bf16x8 bF[4];
#pragma unroll
        for (int nb = 0; nb < 4; ++nb)
            bF[nb] = *(const bf16x8*)(cbp + nb * (16 * 512) + kb);
        SB;

        // WAR: both waves done reading buf(cur^1) before overwrite.
        asm volatile("s_waitcnt lgkmcnt(0)" ::: "memory");
        __builtin_amdgcn_s_barrier();
        SB;

        if (it < 15) {
            STAGE(cur ^ 1, kb + 32);
            SB;
            // Drain stage(t)+B(t) (older); leave stage(t+1) (4) in flight.
            asm volatile("s_waitcnt vmcnt(4)" ::: "memory");
        } else {
            asm volatile("s_waitcnt vmcnt(0)" ::: "memory");
        }
        SB;
        __builtin_amdgcn_s_barrier();   // tile `it` fully in LDS (both halves)
        SB;

        // Compute: per rb build A-frag from swizzled LDS, then 4 MFMA.
#pragma unroll
        for (int rb = 0; rb < 4; ++rb) {
            const float* bw = &lds[cur][(rb * 16 + m) * 32];
            f32x4 u0 = *(const f32x4*)(bw + (((2 * g)     ^ (m & 7)) * 4));
            f32x4 u1 = *(const f32x4*)(bw + (((2 * g + 1) ^ (m & 7)) * 4));
            bf16x8 aF;
#pragma unroll
            for (int j = 0; j < 4; ++j) {
                aF[j]     = (__bf16)u0[j];
                aF[4 + j] = (__bf16)u1[j];
                x2p[rb] += u0[j] * u0[j];
                x2p[rb] += u1[j] * u1[j];
            }
            __builtin_amdgcn_s_setprio(1);
#pragma unroll
            for (int nb = 0; nb < 4; ++nb)
                acc[rb][nb] = __builtin_amdgcn_mfma_f32_16x16x32_bf16(
                    aF, bF[nb], acc[rb][nb], 0, 0, 0);
            __builtin_amdgcn_s_setprio(0);
        }
    }
#undef STAGE

    // Complete x2 across k-groups (this wave read all k for its rows).
#pragma unroll
    for (int rb = 0; rb < 4; ++rb) {
        x2p[rb] += __shfl_xor(x2p[rb], 16);
        x2p[rb] += __shfl_xor(x2p[rb], 32);
    }

    float c2v[4];
#pragma unroll
    for (int nb = 0; nb < 4; ++nb) c2v[nb] = c2[w * 64 + nb * 16 + m];

    // Pass A: q in place; per-wave partial row sums -> rsx[w].
#pragma unroll
    for (int rb = 0; rb < 4; ++rb) {
        float x2r[4], rs[4];
#pragma unroll
        for (int r = 0; r < 4; ++r) {
            x2r[r] = __shfl(x2p[rb], g * 4 + r);
            rs[r] = 0.f;
        }
#pragma unroll
        for (int nb = 0; nb < 4; ++nb) {
#pragma unroll
            for (int r = 0; r < 4; ++r) {
                float d2 = x2r[r] + c2v[nb] - 2.f * acc[rb][nb][r];
                d2 = fmaxf(d2, 0.f);
                float q = 1.f / (1.f + d2);   // ALPHA=1 -> exponent is 1
                acc[rb][nb][r] = q;
                rs[r] += q;
            }
        }
#pragma unroll
        for (int r = 0; r < 4; ++r) {
            rs[r] += __shfl_xor(rs[r], 1);
            rs[r] += __shfl_xor(rs[r], 2);
            rs[r] += __shfl_xor(rs[r], 4);
            rs[r] += __shfl_xor(rs[r], 8);
        }
        if (m == 0) {
#pragma unroll
            for (int r = 0; r < 4; ++r) rsx[w][rb * 16 + g * 4 + r] = rs[r];
        }
    }
    asm volatile("s_waitcnt lgkmcnt(0)" ::: "memory");
    __builtin_amdgcn_s_barrier();

    // Pass B: total row sums, normalize, write.
#pragma unroll
    for (int rb = 0; rb < 4; ++rb) {
        float inv[4];
#pragma unroll
        for (int r = 0; r < 4; ++r) {
            const int row = rb * 16 + g * 4 + r;
            inv[r] = 1.f / (rsx[0][row] + rsx[1][row]);
        }
        const long orow = brow + rb * 16 + g * 4;
#pragma unroll
        for (int nb = 0; nb < 4; ++nb) {
#pragma unroll
            for (int r = 0; r < 4; ++r) {
                out[(orow + r) * 128 + w * 64 + nb * 16 + m] =
                    acc[rb][nb][r] * inv[r];
            }
        }
    }
#undef SB
}

extern "C" void kernel_launch(void* const* d_in, const int* in_sizes, int n_in,
                              void* d_out, int out_size, void* d_ws, size_t ws_size,
                              hipStream_t stream)
{
    const float* x = (const float*)d_in[0];
    const float* c = (const float*)d_in[1];
    float* out = (float*)d_out;

    float*  c2ws = (float*)d_ws;                        // 128 floats
    __bf16* cbws = (__bf16*)((char*)d_ws + 1024);       // 128x512 bf16 = 128 KB

    hipLaunchKernelGGL(prep_clusters, dim3(128), dim3(64), 0, stream, c, cbws, c2ws);

    const int N = in_sizes[0] / 512;                    // 131072 rows
    dim3 grid(N / 64), block(128);                      // 2048 blocks = 8/CU
    hipLaunchKernelGGL(cluster_q_mfma, grid, block, 0, stream, x, cbws, c2ws, out);
}

// Round 7
// 86.314 us; speedup vs baseline: 1.4075x; 1.0368x over previous
//
#include <hip/hip_runtime.h>
#include <hip/hip_bf16.h>

typedef __bf16 bf16x8 __attribute__((ext_vector_type(8)));
typedef float f32x4 __attribute__((ext_vector_type(4)));

// Pre-kernel: clusters (128x512 f32) -> bf16 in ws, plus fp32 c2[128].
__global__ __launch_bounds__(64)
void prep_clusters(const float* __restrict__ c, __bf16* __restrict__ cb,
                   float* __restrict__ c2)
{
    const int row = blockIdx.x;     // 0..127
    const int l = threadIdx.x;      // 0..63
    const float* p = c + row * 512 + l * 8;
    f32x4 u0 = *(const f32x4*)p;
    f32x4 u1 = *(const f32x4*)(p + 4);
    bf16x8 v;
    float s = 0.f;
#pragma unroll
    for (int j = 0; j < 4; ++j) {
        v[j]     = (__bf16)u0[j];
        v[4 + j] = (__bf16)u1[j];
        s += u0[j] * u0[j] + u1[j] * u1[j];
    }
    *(bf16x8*)(cb + row * 512 + l * 8) = v;
#pragma unroll
    for (int off = 32; off >= 1; off >>= 1) s += __shfl_xor(s, off);
    if (l == 0) c2[row] = s;
}

__device__ __forceinline__ void gl_lds16(const float* g, float* l)
{
    __builtin_amdgcn_global_load_lds(
        (const __attribute__((address_space(1))) void*)g,
        (__attribute__((address_space(3))) void*)l, 16, 0, 0);
}

// FULL-ROW STAGING: 512 persistent blocks (2/CU), each owns 256 consecutive
// rows processed in 16 passes of 16 rows. Per pass the block stages 16 full
// rows (32 KB CONTIGUOUS; each global_load_lds covers a contiguous 1 KB) into
// a double-buffered LDS tile — no more 128B-at-2KB-stride scatter. B (bf16
// clusters) lives in REGISTERS for the whole kernel (wave owns 32 cols ->
// bR[2][16] = 128 VGPRs), so the K-loop has zero global loads. LDS chunks are
// XOR-swizzled within 128-B groups (both sides) so fragment ds_reads are
// 2-way max (free) while global requests stay contiguous.
__global__ __launch_bounds__(256, 2)
void cluster_q_mfma(const float* __restrict__ x,
                    const __bf16* __restrict__ cb,
                    const float* __restrict__ c2,
                    float* __restrict__ out)
{
    __shared__ float lds[2][16 * 512];   // 2 x 32 KB full-row tiles
    __shared__ float rsx[4][16];         // per-wave partial row sums

    const int tid = threadIdx.x;
    const int l = tid & 63;
    const int w = tid >> 6;         // wave 0..3: owns cols w*32 .. w*32+31
    const int m = l & 15;           // fragment row (A) / col (B)
    const int g = l >> 4;           // k-group 0..3
    const long brow = (long)blockIdx.x * 256;

    // c2 for this wave's two column fragments (2 VMEM loads, drained by vmcnt)
    float c2v[2];
#pragma unroll
    for (int nb = 0; nb < 2; ++nb) c2v[nb] = c2[w * 32 + nb * 16 + m];

    // Persistent B: cols w*32+nb*16+m, all 512 k. 32 x b128 loads, 128 VGPRs.
    bf16x8 bR[2][16];
#pragma unroll
    for (int nb = 0; nb < 2; ++nb)
#pragma unroll
        for (int ks = 0; ks < 16; ++ks)
            bR[nb][ks] = *(const bf16x8*)(
                cb + (w * 32 + nb * 16 + m) * 512 + ks * 32 + g * 8);

    // Staging pre-swizzle: instr i_ covers tile-row w*4+(i_>>1), half i_&1.
    // Lane l's source chunk within the half: low-3 bits XOR (row & 7) — a
    // permutation inside each aligned 128-B group, so the instruction's 64
    // lanes still cover exactly one contiguous 1-KB span.
    int co[4];
#pragma unroll
    for (int q = 0; q < 4; ++q)
        co[q] = (l & 56) + ((l & 7) ^ ((w * 4 + q) & 7));

    // LDS read bases (bytes): row m, chunks (ks*8 + (2g|2g+1)^(m&7)).
    const int rbo0 = m * 2048 + (((2 * g)     ^ (m & 7)) * 16);
    const int rbo1 = m * 2048 + (((2 * g + 1) ^ (m & 7)) * 16);

#define SB __builtin_amdgcn_sched_barrier(0)
#define STAGE(BUF, P)                                                     \
    { _Pragma("unroll")                                                   \
      for (int i_ = 0; i_ < 8; ++i_) {                                    \
          const int q_ = i_ >> 1, h_ = i_ & 1;                            \
          gl_lds16(x + (brow + (long)(P) * 16 + w * 4 + q_) * 512         \
                     + h_ * 256 + co[q_] * 4,                             \
                   &lds[BUF][(w * 4 + q_) * 512 + h_ * 256]);             \
      } }

    STAGE(0, 0);                      // pass-0 tile in flight

#pragma unroll 1
    for (int p = 0; p < 16; ++p) {
        const int cur = p & 1;

        // WAR: everyone done reading lds[cur^1] and rsx before overwrite.
        asm volatile("s_waitcnt lgkmcnt(0)" ::: "memory");
        __builtin_amdgcn_s_barrier();
        SB;
        if (p < 15) {
            STAGE(cur ^ 1, p + 1);
            SB;
            // Drain tile p (+ prologue loads on p=0); leave tile p+1 in flight.
            asm volatile("s_waitcnt vmcnt(8)" ::: "memory");
        } else {
            asm volatile("s_waitcnt vmcnt(0)" ::: "memory");
        }
        SB;
        __builtin_amdgcn_s_barrier();   // tile p fully in LDS
        SB;

        f32x4 acc[2] = {f32x4{0.f, 0.f, 0.f, 0.f}, f32x4{0.f, 0.f, 0.f, 0.f}};
        float x2p = 0.f;
        const char* L = (const char*)&lds[cur][0];

#pragma unroll
        for (int ks = 0; ks < 16; ++ks) {
            f32x4 u0 = *(const f32x4*)(L + rbo0 + ks * 128);
            f32x4 u1 = *(const f32x4*)(L + rbo1 + ks * 128);
            bf16x8 aF;
#pragma unroll
            for (int j = 0; j < 4; ++j) {
                aF[j]     = (__bf16)u0[j];
                aF[4 + j] = (__bf16)u1[j];
                x2p += u0[j] * u0[j] + u1[j] * u1[j];
            }
            acc[0] = __builtin_amdgcn_mfma_f32_16x16x32_bf16(aF, bR[0][ks], acc[0], 0, 0, 0);
            acc[1] = __builtin_amdgcn_mfma_f32_16x16x32_bf16(aF, bR[1][ks], acc[1], 0, 0, 0);
        }

        // Complete x2 (lane (m,g) holds a quarter of row m's sum).
        x2p += __shfl_xor(x2p, 16);
        x2p += __shfl_xor(x2p, 32);

        float x2r[4], rs[4];
#pragma unroll
        for (int r = 0; r < 4; ++r) {
            x2r[r] = __shfl(x2p, g * 4 + r);   // x2 of output row g*4+r
            rs[r] = 0.f;
        }
#pragma unroll
        for (int nb = 0; nb < 2; ++nb)
#pragma unroll
            for (int r = 0; r < 4; ++r) {
                float d2 = fmaxf(x2r[r] + c2v[nb] - 2.f * acc[nb][r], 0.f);
                float qv = 1.f / (1.f + d2);    // ALPHA=1 -> exponent 1
                acc[nb][r] = qv;
                rs[r] += qv;
            }
#pragma unroll
        for (int r = 0; r < 4; ++r) {
            rs[r] += __shfl_xor(rs[r], 1);
            rs[r] += __shfl_xor(rs[r], 2);
            rs[r] += __shfl_xor(rs[r], 4);
            rs[r] += __shfl_xor(rs[r], 8);
        }
        if (m == 0) {
#pragma unroll
            for (int r = 0; r < 4; ++r) rsx[w][g * 4 + r] = rs[r];
        }
        asm volatile("s_waitcnt lgkmcnt(0)" ::: "memory");
        __builtin_amdgcn_s_barrier();   // partial sums visible to all waves
        SB;

        const long orow = brow + p * 16 + g * 4;
#pragma unroll
        for (int r = 0; r < 4; ++r) {
            const int row16 = g * 4 + r;
            const float inv = 1.f / (rsx[0][row16] + rsx[1][row16] +
                                     rsx[2][row16] + rsx[3][row16]);
#pragma unroll
            for (int nb = 0; nb < 2; ++nb)
                out[(orow + r) * 128 + w * 32 + nb * 16 + m] = acc[nb][r] * inv;
        }
    }
#undef STAGE
#undef SB
}

extern "C" void kernel_launch(void* const* d_in, const int* in_sizes, int n_in,
                              void* d_out, int out_size, void* d_ws, size_t ws_size,
                              hipStream_t stream)
{
    const float* x = (const float*)d_in[0];
    const float* c = (const float*)d_in[1];
    float* out = (float*)d_out;

    float*  c2ws = (float*)d_ws;                        // 128 floats
    __bf16* cbws = (__bf16*)((char*)d_ws + 1024);       // 128x512 bf16 = 128 KB

    hipLaunchKernelGGL(prep_clusters, dim3(128), dim3(64), 0, stream, c, cbws, c2ws);

    const int N = in_sizes[0] / 512;                    // 131072 rows
    dim3 grid(N / 256), block(256);                     // 512 blocks = 2/CU
    hipLaunchKernelGGL(cluster_q_mfma, grid, block, 0, stream, x, cbws, c2ws, out);
}

// Round 8
// 82.206 us; speedup vs baseline: 1.4779x; 1.0500x over previous
//
#include <hip/hip_runtime.h>
#include <hip/hip_bf16.h>

typedef __bf16 bf16x8 __attribute__((ext_vector_type(8)));
typedef float f32x4 __attribute__((ext_vector_type(4)));

// Pre-kernel: clusters (128x512 f32) -> bf16 in ws, plus fp32 c2[128].
__global__ __launch_bounds__(64)
void prep_clusters(const float* __restrict__ c, __bf16* __restrict__ cb,
                   float* __restrict__ c2)
{
    const int row = blockIdx.x;     // 0..127
    const int l = threadIdx.x;      // 0..63
    const float* p = c + row * 512 + l * 8;
    f32x4 u0 = *(const f32x4*)p;
    f32x4 u1 = *(const f32x4*)(p + 4);
    bf16x8 v;
    float s = 0.f;
#pragma unroll
    for (int j = 0; j < 4; ++j) {
        v[j]     = (__bf16)u0[j];
        v[4 + j] = (__bf16)u1[j];
        s += u0[j] * u0[j] + u1[j] * u1[j];
    }
    *(bf16x8*)(cb + row * 512 + l * 8) = v;
#pragma unroll
    for (int off = 32; off >= 1; off >>= 1) s += __shfl_xor(s, off);
    if (l == 0) c2[row] = s;
}

// REG-STAGED STREAMING (T14): x is read with plain global_load_dwordx4 into
// registers (the instruction m13's 6.29 TB/s copy uses), issued at pass top so
// the whole compute+epilogue phase covers HBM latency; written to a SINGLE
// 32 KB LDS tile at pass end (vmcnt(8) counted wait -> never blocks on fresh
// loads). This removes global_load_lds from the x path entirely — the one
// component shared by all five ~3.6 TB/s-capped variants. B stays persistent
// in registers (128 VGPR); swizzle moved to the ds_write address (global loads
// perfectly linear); reads identical to R7.
__global__ __launch_bounds__(256, 2)
void cluster_q_mfma(const float* __restrict__ x,
                    const __bf16* __restrict__ cb,
                    const float* __restrict__ c2,
                    float* __restrict__ out)
{
    __shared__ float lds[16 * 512];      // one 32 KB tile (16 rows x 512)
    __shared__ float rsx[4][16];         // per-wave partial row sums

    const int tid = threadIdx.x;
    const int l = tid & 63;
    const int w = tid >> 6;         // wave 0..3: owns cols w*32 .. w*32+31
    const int m = l & 15;           // fragment row (A) / col (B)
    const int g = l >> 4;           // k-group 0..3
    const long brow = (long)blockIdx.x * 256;

    float c2v[2];
#pragma unroll
    for (int nb = 0; nb < 2; ++nb) c2v[nb] = c2[w * 32 + nb * 16 + m];

    // Persistent B: cols w*32+nb*16+m, all 512 k. 32 x b128 loads, 128 VGPRs.
    bf16x8 bR[2][16];
#pragma unroll
    for (int nb = 0; nb < 2; ++nb)
#pragma unroll
        for (int ks = 0; ks < 16; ++ks)
            bR[nb][ks] = *(const bf16x8*)(
                cb + (w * 32 + nb * 16 + m) * 512 + ks * 32 + g * 8);

    // Staging geometry: instr i_ covers tile-row w*4+(i_>>1), half h=i_&1.
    // Global load: lane l takes chunk l of the 1 KB half (fully linear).
    // ds_write chunk position: low-3 bits XOR (row&7)  (both-sides swizzle,
    // now applied on the LDS-write side).
    int cow[4];
#pragma unroll
    for (int q = 0; q < 4; ++q)
        cow[q] = (l & 56) + ((l & 7) ^ ((w * 4 + q) & 7));

    // LDS read bases (bytes): row m, chunk (ks*8 + (2g|2g+1)^(m&7)).
    const int rbo0 = m * 2048 + (((2 * g)     ^ (m & 7)) * 16);
    const int rbo1 = m * 2048 + (((2 * g + 1) ^ (m & 7)) * 16);

    f32x4 G[8];

#define SB __builtin_amdgcn_sched_barrier(0)
#define GLOAD(P)                                                          \
    { _Pragma("unroll")                                                   \
      for (int i_ = 0; i_ < 8; ++i_)                                      \
          G[i_] = *(const f32x4*)(x + (brow + (long)(P) * 16              \
                     + w * 4 + (i_ >> 1)) * 512 + (i_ & 1) * 256 + l * 4); }
#define DSWRITE()                                                         \
    { _Pragma("unroll")                                                   \
      for (int i_ = 0; i_ < 8; ++i_)                                      \
          *(f32x4*)(&lds[(w * 4 + (i_ >> 1)) * 512 + (i_ & 1) * 256       \
                         + cow[i_ >> 1] * 4]) = G[i_]; }

    // Prologue: tile 0 through registers into LDS.
    GLOAD(0);
    asm volatile("s_waitcnt vmcnt(0)" ::: "memory");
    DSWRITE();
    asm volatile("s_waitcnt lgkmcnt(0)" ::: "memory");
    __builtin_amdgcn_s_barrier();

#pragma unroll 1
    for (int p = 0; p < 16; ++p) {
        // P1: issue next tile's loads early (latency hides under compute).
        if (p < 15) { GLOAD(p + 1); }
        SB;

        // P2: compute pass p from LDS.
        f32x4 acc[2] = {f32x4{0.f, 0.f, 0.f, 0.f}, f32x4{0.f, 0.f, 0.f, 0.f}};
        float x2p = 0.f;
        const char* L = (const char*)&lds[0];
#pragma unroll
        for (int ks = 0; ks < 16; ++ks) {
            f32x4 u0 = *(const f32x4*)(L + rbo0 + ks * 128);
            f32x4 u1 = *(const f32x4*)(L + rbo1 + ks * 128);
            bf16x8 aF;
#pragma unroll
            for (int j = 0; j < 4; ++j) {
                aF[j]     = (__bf16)u0[j];
                aF[4 + j] = (__bf16)u1[j];
                x2p += u0[j] * u0[j] + u1[j] * u1[j];
            }
            acc[0] = __builtin_amdgcn_mfma_f32_16x16x32_bf16(aF, bR[0][ks], acc[0], 0, 0, 0);
            acc[1] = __builtin_amdgcn_mfma_f32_16x16x32_bf16(aF, bR[1][ks], acc[1], 0, 0, 0);
        }

        // P3: softmax-style epilogue for these 16 rows.
        x2p += __shfl_xor(x2p, 16);
        x2p += __shfl_xor(x2p, 32);

        float x2r[4], rs[4];
#pragma unroll
        for (int r = 0; r < 4; ++r) {
            x2r[r] = __shfl(x2p, g * 4 + r);
            rs[r] = 0.f;
        }
#pragma unroll
        for (int nb = 0; nb < 2; ++nb)
#pragma unroll
            for (int r = 0; r < 4; ++r) {
                float d2 = fmaxf(x2r[r] + c2v[nb] - 2.f * acc[nb][r], 0.f);
                float qv = __builtin_amdgcn_rcpf(1.f + d2);  // ALPHA=1
                acc[nb][r] = qv;
                rs[r] += qv;
            }
#pragma unroll
        for (int r = 0; r < 4; ++r) {
            rs[r] += __shfl_xor(rs[r], 1);
            rs[r] += __shfl_xor(rs[r], 2);
            rs[r] += __shfl_xor(rs[r], 4);
            rs[r] += __shfl_xor(rs[r], 8);
        }
        if (m == 0) {
#pragma unroll
            for (int r = 0; r < 4; ++r) rsx[w][g * 4 + r] = rs[r];
        }
        asm volatile("s_waitcnt lgkmcnt(0)" ::: "memory");
        __builtin_amdgcn_s_barrier();      // BARRIER-A: rsx ready, tile reads done

        const long orow = brow + p * 16 + g * 4;
#pragma unroll
        for (int r = 0; r < 4; ++r) {
            const int row16 = g * 4 + r;
            const float inv = __builtin_amdgcn_rcpf(
                rsx[0][row16] + rsx[1][row16] + rsx[2][row16] + rsx[3][row16]);
#pragma unroll
            for (int nb = 0; nb < 2; ++nb)
                out[(orow + r) * 128 + w * 32 + nb * 16 + m] = acc[nb][r] * inv;
        }

        // P4-P7: land next tile in LDS (counted wait: 8 newest = this pass's
        // stores stay in flight; the 8 G-loads — older — are drained).
        if (p < 15) {
            asm volatile("s_waitcnt vmcnt(8)" ::: "memory");
            SB;
            DSWRITE();
            asm volatile("s_waitcnt lgkmcnt(0)" ::: "memory");
            __builtin_amdgcn_s_barrier();  // BARRIER-B: tile p+1 visible to all
        }
    }
#undef GLOAD
#undef DSWRITE
#undef SB
}

extern "C" void kernel_launch(void* const* d_in, const int* in_sizes, int n_in,
                              void* d_out, int out_size, void* d_ws, size_t ws_size,
                              hipStream_t stream)
{
    const float* x = (const float*)d_in[0];
    const float* c = (const float*)d_in[1];
    float* out = (float*)d_out;

    float*  c2ws = (float*)d_ws;                        // 128 floats
    __bf16* cbws = (__bf16*)((char*)d_ws + 1024);       // 128x512 bf16 = 128 KB

    hipLaunchKernelGGL(prep_clusters, dim3(128), dim3(64), 0, stream, c, cbws, c2ws);

    const int N = in_sizes[0] / 512;                    // 131072 rows
    dim3 grid(N / 256), block(256);                     // 512 blocks = 2/CU
    hipLaunchKernelGGL(cluster_q_mfma, grid, block, 0, stream, x, cbws, c2ws, out);
}